// Round 2
// baseline (194.084 us; speedup 1.0000x reference)
//
#include <hip/hip_runtime.h>
#include <math.h>

// HomoAttention monolith (R8). 2048 blocks x 512 threads (8 waves).
// Per (b,n): x[F=8][E=32], z[K=64][F][E]; L2-normalize over E; a[k][f]=cos sim;
// softmax over k; u = sum_k a*zn. neigh = 134 MB read-once, out 2 MB (nt store).
//
// R8 change vs R7 (184.1us):
//  - Loads are now PLAIN (no nontemporal hint). The input buffer is rewritten
//    by the harness restore every iteration and at 134 MB fits in the 256 MB
//    Infinity Cache; nt loads bypass/stream past the cache and forfeit L3
//    hits. Read-once => no pollution downside to cached loads (L3 > working
//    set). If the 536 MB per-iter fill thrashes L3 first, this is neutral and
//    we are at the harness floor.
//  - nt kept on the output store (write-once, avoid displacing input lines).
//
// R7 (184.1us): register-resident softmax, p[i]=exp(d) computed once, per-wave
// partial denominators through 256 B LDS; no max-shift (cosines in [-1,1]).

#define NF 8
#define DD 256
#define KK 64

typedef float f4 __attribute__((ext_vector_type(4)));

__global__ __launch_bounds__(512)
void homo_attn_kernel(const float* __restrict__ features,
                      const float* __restrict__ neigh,
                      float* __restrict__ out)
{
    const int bn = blockIdx.x;
    const int t  = threadIdx.x;
    const int l  = t & 63;   // lane
    const int tg = t >> 6;   // wave 0..7
    const int f  = l >> 3;   // facet
    const int sub = l & 7;

    const float* xp = features + (size_t)bn * DD;
    const float* zp = neigh    + (size_t)bn * (KK * DD);

    // ---- batch x load + this wave's 8 z-row loads (all in flight) ----
    f4 xv = ((const f4*)xp)[l];
    f4 zr[8];
#pragma unroll
    for (int i = 0; i < 8; ++i) {
        const int k = i * 8 + tg;
        zr[i] = ((const f4*)(zp + k * DD))[l];
    }
    __builtin_amdgcn_sched_barrier(0);

    // ---- normalize x fragment ----
    float ss = xv.x*xv.x + xv.y*xv.y + xv.z*xv.z + xv.w*xv.w;
    ss += __shfl_xor(ss, 1);
    ss += __shfl_xor(ss, 2);
    ss += __shfl_xor(ss, 4);
    float xs = 1.0f / fmaxf(sqrtf(ss), 1e-12f);
    xv *= xs;

    __shared__ float dpart[8][NF];   // 256 B per-wave partial denominators
    __shared__ f4    part[8][64];    // 8 KB cross-wave output partials

    // ---- normalize z, cosine scores, exp in-register, partial denom ----
    float p[8];
    float s = 0.0f;
#pragma unroll
    for (int i = 0; i < 8; ++i) {
        f4 z = zr[i];
        float zss = z.x*z.x + z.y*z.y + z.z*z.z + z.w*z.w;
        zss += __shfl_xor(zss, 1);
        zss += __shfl_xor(zss, 2);
        zss += __shfl_xor(zss, 4);
        float zs = 1.0f / fmaxf(sqrtf(zss), 1e-12f);
        z *= zs;
        zr[i] = z;
        float d = z.x*xv.x + z.y*xv.y + z.z*xv.z + z.w*xv.w;
        d += __shfl_xor(d, 1);
        d += __shfl_xor(d, 2);
        d += __shfl_xor(d, 4);
        const float pi = __expf(d);   // all 8 sub-lanes hold identical d/pi
        p[i] = pi;
        s += pi;
    }
    // s = sum of exp over this wave's 8 k's (identical across sub-lanes)
    if (sub == 0) dpart[tg][f] = s;
    __syncthreads();

    // ---- full denominator: sum 8 wave-partials (broadcast LDS reads) ----
    float denom = 0.0f;
#pragma unroll
    for (int w = 0; w < 8; ++w) denom += dpart[w][f];
    const float inv = 1.0f / denom;

    // ---- weighted partial sum over this wave's 8 k's (registers only) ----
    f4 u = (f4)(0.f, 0.f, 0.f, 0.f);
#pragma unroll
    for (int i = 0; i < 8; ++i) u += p[i] * zr[i];
    u *= inv;

    part[tg][l] = u;
    __syncthreads();

    // ---- combine 8 wave partials, store ----
    if (tg == 0) {
        f4 r = (part[0][l] + part[1][l]) + (part[2][l] + part[3][l])
             + (part[4][l] + part[5][l]) + (part[6][l] + part[7][l]);
        __builtin_nontemporal_store(r, ((f4*)(out + (size_t)bn * DD)) + l);
    }
}

extern "C" void kernel_launch(void* const* d_in, const int* in_sizes, int n_in,
                              void* d_out, int out_size, void* d_ws, size_t ws_size,
                              hipStream_t stream) {
    const float* features = (const float*)d_in[0];
    const float* neigh    = (const float*)d_in[1];
    float* out            = (float*)d_out;
    const int BN = in_sizes[0] / DD;   // 128*16 = 2048
    homo_attn_kernel<<<BN, 512, 0, stream>>>(features, neigh, out);
}

// Round 3
// 183.561 us; speedup vs baseline: 1.0573x; 1.0573x over previous
//
#include <hip/hip_runtime.h>
#include <math.h>

// HomoAttention monolith (R9 = revert to R7, session best 184.1us).
// 2048 blocks x 512 threads (8 waves).
// Per (b,n): x[F=8][E=32], z[K=64][F][E]; L2-normalize over E; a[k][f]=cos sim;
// softmax over k; u = sum_k a*zn. neigh = 134 MB read-once (nt), out 2 MB (nt).
//
// R8 EXPERIMENT (FAILED, 194.1us): plain cached loads hoping for L3-warm
// inputs. Regressed 10us -> the 512 MiB per-iter poison fill (WRITE_SIZE
// counter) thrashes Infinity Cache between restore and kernel; inputs are
// cold, and cached allocation of a read-once stream costs ~10us vs nt.
// CONCLUSION: nt loads are correct for this harness. Do not retry.
//
// R7 (184.1us): register-resident softmax: p[i]=exp(d) computed ONCE at score
// time, kept in p[8]; per-(wave,facet) partial denominators reduced through a
// 256 B LDS buffer (8 LDS reads/thread vs R6's 72); inv folded into one f4
// post-scale. No max-subtraction: scores are cosines in [-1,1] (Cauchy-
// Schwarz after normalization), exp in [0.37,2.72].

#define NF 8
#define DD 256
#define KK 64

typedef float f4 __attribute__((ext_vector_type(4)));

__global__ __launch_bounds__(512)
void homo_attn_kernel(const float* __restrict__ features,
                      const float* __restrict__ neigh,
                      float* __restrict__ out)
{
    const int bn = blockIdx.x;
    const int t  = threadIdx.x;
    const int l  = t & 63;   // lane
    const int tg = t >> 6;   // wave 0..7
    const int f  = l >> 3;   // facet
    const int sub = l & 7;

    const float* xp = features + (size_t)bn * DD;
    const float* zp = neigh    + (size_t)bn * (KK * DD);

    // ---- batch x load + this wave's 8 z-row loads (all in flight) ----
    f4 xv = ((const f4*)xp)[l];
    f4 zr[8];
#pragma unroll
    for (int i = 0; i < 8; ++i) {
        const int k = i * 8 + tg;
        zr[i] = __builtin_nontemporal_load(((const f4*)(zp + k * DD)) + l);
    }
    __builtin_amdgcn_sched_barrier(0);

    // ---- normalize x fragment ----
    float ss = xv.x*xv.x + xv.y*xv.y + xv.z*xv.z + xv.w*xv.w;
    ss += __shfl_xor(ss, 1);
    ss += __shfl_xor(ss, 2);
    ss += __shfl_xor(ss, 4);
    float xs = 1.0f / fmaxf(sqrtf(ss), 1e-12f);
    xv *= xs;

    __shared__ float dpart[8][NF];   // 256 B per-wave partial denominators
    __shared__ f4    part[8][64];    // 8 KB cross-wave output partials

    // ---- normalize z, cosine scores, exp in-register, partial denom ----
    float p[8];
    float s = 0.0f;
#pragma unroll
    for (int i = 0; i < 8; ++i) {
        f4 z = zr[i];
        float zss = z.x*z.x + z.y*z.y + z.z*z.z + z.w*z.w;
        zss += __shfl_xor(zss, 1);
        zss += __shfl_xor(zss, 2);
        zss += __shfl_xor(zss, 4);
        float zs = 1.0f / fmaxf(sqrtf(zss), 1e-12f);
        z *= zs;
        zr[i] = z;
        float d = z.x*xv.x + z.y*xv.y + z.z*xv.z + z.w*xv.w;
        d += __shfl_xor(d, 1);
        d += __shfl_xor(d, 2);
        d += __shfl_xor(d, 4);
        const float pi = __expf(d);   // all 8 sub-lanes hold identical d/pi
        p[i] = pi;
        s += pi;
    }
    // s = sum of exp over this wave's 8 k's (identical across sub-lanes)
    if (sub == 0) dpart[tg][f] = s;
    __syncthreads();

    // ---- full denominator: sum 8 wave-partials (broadcast LDS reads) ----
    float denom = 0.0f;
#pragma unroll
    for (int w = 0; w < 8; ++w) denom += dpart[w][f];
    const float inv = 1.0f / denom;

    // ---- weighted partial sum over this wave's 8 k's (registers only) ----
    f4 u = (f4)(0.f, 0.f, 0.f, 0.f);
#pragma unroll
    for (int i = 0; i < 8; ++i) u += p[i] * zr[i];
    u *= inv;

    part[tg][l] = u;
    __syncthreads();

    // ---- combine 8 wave partials, store ----
    if (tg == 0) {
        f4 r = (part[0][l] + part[1][l]) + (part[2][l] + part[3][l])
             + (part[4][l] + part[5][l]) + (part[6][l] + part[7][l]);
        __builtin_nontemporal_store(r, ((f4*)(out + (size_t)bn * DD)) + l);
    }
}

extern "C" void kernel_launch(void* const* d_in, const int* in_sizes, int n_in,
                              void* d_out, int out_size, void* d_ws, size_t ws_size,
                              hipStream_t stream) {
    const float* features = (const float*)d_in[0];
    const float* neigh    = (const float*)d_in[1];
    float* out            = (float*)d_out;
    const int BN = in_sizes[0] / DD;   // 128*16 = 2048
    homo_attn_kernel<<<BN, 512, 0, stream>>>(features, neigh, out);
}